// Round 1
// baseline (92.626 us; speedup 1.0000x reference)
//
#include <hip/hip_runtime.h>
#include <hip/hip_bf16.h>

// Problem: B=8, C=64, H=W=64, N=4096, P=1024.
// ws layout (bf16 elements):
//   Kt (B,N,C) @ 0          : stage-1 keys,  row-major over C
//   Vc (B,C,N) @ 2097152    : stage-1 values (channel-major)
//   Qt (B,N,C) @ 4194304    : stage-2 queries
//   qt (B,P,C) @ 6291456    : pooled q (stage-1 queries / stage-2 keys)
//   O1 (B,C,P) @ 6815744    : stage-1 out (stage-2 values)
// total 7,340,032 el = 14.7 MB

typedef float  f32x4  __attribute__((ext_vector_type(4)));
typedef __bf16 bf16x8 __attribute__((ext_vector_type(8)));
typedef __bf16 bf16x4 __attribute__((ext_vector_type(4)));

// chunk (16B) XOR swizzle: row = ch>>3 (8 chunks per 128B row), spread over banks
__device__ __forceinline__ int swz(int ch) { return ch ^ ((ch >> 3) & 7); }

// ---------------------------------------------------------------------------
// Kernel 1: four 1x1 convs (+bias), fp32 compute, bf16 outputs in MFMA layouts.
// Block: (b, row-pair rp) -> 64c x 128n tile. 256 thr: (ty,tx) owns 4o x 8n.
// q-branch: 2x2 avg pool fused via shfl_xor(8) (rows h=2rp,2rp+1 are in-tile).
// ---------------------------------------------------------------------------
__global__ __launch_bounds__(256) void conv4_kernel(
    const float* __restrict__ x,
    const float* __restrict__ wq, const float* __restrict__ bq,
    const float* __restrict__ wQ, const float* __restrict__ bQ,
    const float* __restrict__ wK, const float* __restrict__ bK,
    const float* __restrict__ wV, const float* __restrict__ bV,
    __bf16* __restrict__ Kt, __bf16* __restrict__ Vc,
    __bf16* __restrict__ Qt, __bf16* __restrict__ qt)
{
  __shared__ float xs[64 * 132];   // [c][n0..128] padded (+4) against b128 conflicts
  __shared__ float wsh[64 * 68];   // [c][o] transposed weights, padded

  const int tid = threadIdx.x;
  const int b   = blockIdx.x >> 5;
  const int rp  = blockIdx.x & 31;
  const int n0  = rp << 7;

  // stage x tile: 64 rows x 128 floats, coalesced f32x4
  for (int i = tid; i < 64 * 32; i += 256) {
    int c = i >> 5, j = i & 31;
    *(f32x4*)&xs[c * 132 + j * 4] =
        *(const f32x4*)&x[((size_t)(b * 64 + c)) * 4096 + n0 + j * 4];
  }

  const int ty = tid >> 4, tx = tid & 15;

#pragma unroll
  for (int m = 0; m < 4; ++m) {
    const float* wg = (m == 0) ? wK : (m == 1) ? wV : (m == 2) ? wQ : wq;
    const float* bg = (m == 0) ? bK : (m == 1) ? bV : (m == 2) ? bQ : bq;

    __syncthreads();  // protect wsh reuse (and first-iter x tile)
    for (int i = tid; i < 1024; i += 256) {
      int o = i >> 4, c0 = (i & 15) << 2;
      f32x4 v = *(const f32x4*)&wg[o * 64 + c0];
      wsh[(c0 + 0) * 68 + o] = v[0];
      wsh[(c0 + 1) * 68 + o] = v[1];
      wsh[(c0 + 2) * 68 + o] = v[2];
      wsh[(c0 + 3) * 68 + o] = v[3];
    }
    __syncthreads();

    float acc[4][8];
    {
      f32x4 bv = *(const f32x4*)&bg[ty * 4];
#pragma unroll
      for (int i = 0; i < 4; ++i)
#pragma unroll
        for (int j = 0; j < 8; ++j) acc[i][j] = bv[i];
    }

#pragma unroll 4
    for (int c = 0; c < 64; ++c) {
      f32x4 wv = *(const f32x4*)&wsh[c * 68 + ty * 4];
      f32x4 xa = *(const f32x4*)&xs[c * 132 + tx * 8];
      f32x4 xb = *(const f32x4*)&xs[c * 132 + tx * 8 + 4];
#pragma unroll
      for (int i = 0; i < 4; ++i) {
#pragma unroll
        for (int j = 0; j < 4; ++j) {
          acc[i][j]     += wv[i] * xa[j];
          acc[i][j + 4] += wv[i] * xb[j];
        }
      }
    }

    if (m == 0 || m == 2) {            // Kt / Qt : (B,N,C)
      __bf16* dst = (m == 0) ? Kt : Qt;
#pragma unroll
      for (int j = 0; j < 8; ++j) {
        int n = n0 + tx * 8 + j;
        bf16x4 pk;
#pragma unroll
        for (int i = 0; i < 4; ++i) pk[i] = (__bf16)acc[i][j];
        *(bf16x4*)&dst[((size_t)(b * 4096 + n)) * 64 + ty * 4] = pk;
      }
    } else if (m == 1) {               // Vc : (B,C,N)
#pragma unroll
      for (int i = 0; i < 4; ++i) {
        int o = ty * 4 + i;
        bf16x8 pk;
#pragma unroll
        for (int j = 0; j < 8; ++j) pk[j] = (__bf16)acc[i][j];
        *(bf16x8*)&Vc[((size_t)(b * 64 + o)) * 4096 + n0 + tx * 8] = pk;
      }
    } else {                           // q branch: 2x2 avg pool -> qt (B,P,C)
      float pl[4][4];
#pragma unroll
      for (int i = 0; i < 4; ++i)
#pragma unroll
        for (int jj = 0; jj < 4; ++jj)
          pl[i][jj] = acc[i][2 * jj] + acc[i][2 * jj + 1];
#pragma unroll
      for (int i = 0; i < 4; ++i)
#pragma unroll
        for (int jj = 0; jj < 4; ++jj)
          pl[i][jj] += __shfl_xor(pl[i][jj], 8);
      if (tx < 8) {
#pragma unroll
        for (int jj = 0; jj < 4; ++jj) {
          int p = rp * 32 + tx * 4 + jj;
          bf16x4 pk;
#pragma unroll
          for (int i = 0; i < 4; ++i) pk[i] = (__bf16)(0.25f * pl[i][jj]);
          *(bf16x4*)&qt[((size_t)(b * 1024 + p)) * 64 + ty * 4] = pk;
        }
      }
    }
  }
}

// ---------------------------------------------------------------------------
// Kernel 2/3: fused flash attention, bf16 MFMA 16x16x32.
// Block = 512 thr = 8 waves = {2 q-tiles of 16} x {4 kv-splits}.
// Per wave, per 64-kv round:
//   S^T = mfma(K_rows, q_cols)  -> D col = q (lane&15), row = kv (4*lg+r)
//   online softmax entirely on p = lane&15; P -> private swizzled LDS;
//   acc(c,p) += mfma(V_rows, P_cols).
// Cross-split combine through LDS, epilogue fused (FINAL: gamma*o + x, fp32).
// ---------------------------------------------------------------------------
template <int KVLEN, int NQ, bool FINAL>
__global__ __launch_bounds__(512, 4) void attn_kernel(
    const __bf16* __restrict__ Qg,   // (B,NQ,C)    queries
    const __bf16* __restrict__ Kg,   // (B,KVLEN,C) keys
    const __bf16* __restrict__ Vg,   // (B,C,KVLEN) values
    void* __restrict__ outp,         // (B,C,NQ) bf16 | float
    const float* __restrict__ xres,
    const float* __restrict__ gammap)
{
  __shared__ __align__(16) char smem[81920];
  __bf16* Ksm = (__bf16*)smem;              // 4 x 8KB  (per kv-split)
  __bf16* Vsm = (__bf16*)(smem + 32768);    // 4 x 8KB
  __bf16* Psm = (__bf16*)(smem + 65536);    // 8 x 2KB  (per wave, private)

  const int tid  = threadIdx.x;
  const int wave = tid >> 6, lane = tid & 63;
  const int lg = (lane >> 4) & 3, lp = lane & 15;
  const int qt = wave & 1, ks = wave >> 1;
  constexpr int QB  = NQ / 32;
  constexpr int KVQ = KVLEN / 4;
  constexpr int RND = KVQ / 64;
  const int b  = blockIdx.x / QB;
  const int q0 = (blockIdx.x % QB) * 32;

  // query b-fragments (held in registers for the whole kernel)
  const __bf16* qg = Qg + ((size_t)(b * NQ + q0 + qt * 16 + lp)) * 64;
  const bf16x8 qf0 = *(const bf16x8*)(qg + lg * 8);
  const bf16x8 qf1 = *(const bf16x8*)(qg + 32 + lg * 8);

  f32x4 acc[4];
#pragma unroll
  for (int ct = 0; ct < 4; ++ct) acc[ct] = (f32x4){0.f, 0.f, 0.f, 0.f};
  float m_run = -3.0e38f, l_run = 0.0f;

  __bf16* lK = Ksm + ks * 4096;
  __bf16* lV = Vsm + ks * 4096;
  __bf16* lP = Psm + wave * 1024;

  for (int r = 0; r < RND; ++r) {
    const int kv0 = ks * KVQ + r * 64;
    // stage this split's 64-kv K and V tiles (swizzled LDS, coalesced global)
    if (qt == 0) {
      const __bf16* g = Kg + ((size_t)b * KVLEN + kv0) * 64;
#pragma unroll
      for (int w = 0; w < 8; ++w) {
        int s = w * 64 + lane;
        *(bf16x8*)(lK + swz(s) * 8) = *(const bf16x8*)(g + s * 8);
      }
    } else {
      const __bf16* g = Vg + (size_t)b * 64 * KVLEN + kv0;
#pragma unroll
      for (int w = 0; w < 8; ++w) {
        int s = w * 64 + lane;
        *(bf16x8*)(lV + swz(s) * 8) =
            *(const bf16x8*)(g + (size_t)(s >> 3) * KVLEN + (s & 7) * 8);
      }
    }
    __syncthreads();

    // S^T tile: 64 kv x 16 q
    f32x4 S[4];
#pragma unroll
    for (int mt = 0; mt < 4; ++mt) {
      int ch0 = (mt * 16 + lp) * 8 + lg;
      bf16x8 a0 = *(const bf16x8*)(lK + swz(ch0) * 8);
      bf16x8 a1 = *(const bf16x8*)(lK + swz(ch0 + 4) * 8);
      f32x4 z = (f32x4){0.f, 0.f, 0.f, 0.f};
      z = __builtin_amdgcn_mfma_f32_16x16x32_bf16(a0, qf0, z, 0, 0, 0);
      z = __builtin_amdgcn_mfma_f32_16x16x32_bf16(a1, qf1, z, 0, 0, 0);
      S[mt] = z;
    }

    // online softmax; this lane's query column is p = lp
    float tmax = -3.0e38f;
#pragma unroll
    for (int mt = 0; mt < 4; ++mt)
#pragma unroll
      for (int rr = 0; rr < 4; ++rr) tmax = fmaxf(tmax, S[mt][rr]);
    tmax = fmaxf(tmax, __shfl_xor(tmax, 16));
    tmax = fmaxf(tmax, __shfl_xor(tmax, 32));
    float mnew = fmaxf(m_run, tmax);
    float sc = __expf(m_run - mnew);
    float rs = 0.f;
#pragma unroll
    for (int mt = 0; mt < 4; ++mt)
#pragma unroll
      for (int rr = 0; rr < 4; ++rr) {
        float e = __expf(S[mt][rr] - mnew);
        S[mt][rr] = e;
        rs += e;
      }
    rs += __shfl_xor(rs, 16);
    rs += __shfl_xor(rs, 32);
    l_run = l_run * sc + rs;
    m_run = mnew;
#pragma unroll
    for (int ct = 0; ct < 4; ++ct) acc[ct] *= sc;

    // P -> private LDS [p=16][kv=64] bf16, swizzled (8B writes)
#pragma unroll
    for (int mt = 0; mt < 4; ++mt) {
      bf16x4 pk;
#pragma unroll
      for (int rr = 0; rr < 4; ++rr) pk[rr] = (__bf16)S[mt][rr];
      int boff = lp * 128 + mt * 32 + lg * 8;
      *(bf16x4*)((char*)lP + (boff ^ ((lp & 7) << 4))) = pk;
    }

    // PV: acc(c-tile, p) += V_rows x P_cols
    {
      int chp = lp * 8 + lg;
      bf16x8 pf0 = *(const bf16x8*)(lP + swz(chp) * 8);
      bf16x8 pf1 = *(const bf16x8*)(lP + swz(chp + 4) * 8);
#pragma unroll
      for (int ct = 0; ct < 4; ++ct) {
        int chv = (ct * 16 + lp) * 8 + lg;
        bf16x8 v0 = *(const bf16x8*)(lV + swz(chv) * 8);
        bf16x8 v1 = *(const bf16x8*)(lV + swz(chv + 4) * 8);
        acc[ct] = __builtin_amdgcn_mfma_f32_16x16x32_bf16(v0, pf0, acc[ct], 0, 0, 0);
        acc[ct] = __builtin_amdgcn_mfma_f32_16x16x32_bf16(v1, pf1, acc[ct], 0, 0, 0);
      }
    }
    __syncthreads();
  }

  // ---- cross-kv-split combine (K/V LDS regions are dead; reuse) ----
  float2* mlb = (float2*)(smem + 65536);
  if (lg == 0) mlb[wave * 16 + lp] = make_float2(m_run, l_run);
  float* cb = (float*)smem;  // [qt][ks][p=16][c=64] fp32 = 32KB
  {
    float* myc = cb + ((size_t)(qt * 4 + ks) * 16 + lp) * 64;
#pragma unroll
    for (int ct = 0; ct < 4; ++ct)
      *(f32x4*)(myc + ct * 16 + lg * 4) = acc[ct];
  }
  __syncthreads();

  if (wave < 2) {
    const int qtt = wave;
    const int nq = q0 + qtt * 16 + lp;
    float mm[4], lv[4];
    float mstar = -3.0e38f;
#pragma unroll
    for (int s = 0; s < 4; ++s) {
      float2 v = mlb[(s * 2 + qtt) * 16 + lp];
      mm[s] = v.x; lv[s] = v.y;
      mstar = fmaxf(mstar, mm[s]);
    }
    float f[4], lstar = 0.f;
#pragma unroll
    for (int s = 0; s < 4; ++s) {
      f[s] = __expf(mm[s] - mstar);
      lstar += lv[s] * f[s];
    }
    float inv = 1.0f / lstar;
    float g0 = 0.f;
    if constexpr (FINAL) g0 = gammap[0];
#pragma unroll
    for (int ct = 0; ct < 4; ++ct) {
      f32x4 o = (f32x4){0.f, 0.f, 0.f, 0.f};
#pragma unroll
      for (int s = 0; s < 4; ++s) {
        f32x4 t = *(const f32x4*)(cb + ((size_t)(qtt * 4 + s) * 16 + lp) * 64 +
                                  ct * 16 + lg * 4);
        o += f[s] * t;
      }
#pragma unroll
      for (int rr = 0; rr < 4; ++rr) {
        int c = ct * 16 + lg * 4 + rr;
        size_t oi = ((size_t)(b * 64 + c)) * NQ + nq;
        float val = o[rr] * inv;
        if constexpr (FINAL) {
          ((float*)outp)[oi] = g0 * val + xres[oi];
        } else {
          ((__bf16*)outp)[oi] = (__bf16)val;
        }
      }
    }
  }
}

// ---------------------------------------------------------------------------
extern "C" void kernel_launch(void* const* d_in, const int* in_sizes, int n_in,
                              void* d_out, int out_size, void* d_ws, size_t ws_size,
                              hipStream_t stream) {
  const float* x     = (const float*)d_in[0];
  const float* wq    = (const float*)d_in[1];
  const float* bq    = (const float*)d_in[2];
  const float* wQ    = (const float*)d_in[3];
  const float* bQ    = (const float*)d_in[4];
  const float* wK    = (const float*)d_in[5];
  const float* bK    = (const float*)d_in[6];
  const float* wV    = (const float*)d_in[7];
  const float* bV    = (const float*)d_in[8];
  const float* gamma = (const float*)d_in[9];

  __bf16* ws = (__bf16*)d_ws;
  __bf16* Kt = ws;
  __bf16* Vc = ws + 2097152;
  __bf16* Qt = ws + 4194304;
  __bf16* qt = ws + 6291456;
  __bf16* O1 = ws + 6815744;

  hipLaunchKernelGGL(conv4_kernel, dim3(256), dim3(256), 0, stream,
                     x, wq, bq, wQ, bQ, wK, bK, wV, bV, Kt, Vc, Qt, qt);
  // stage 1: pooled queries (P=1024) over keys K (N=4096), values V -> O1 (B,C,P)
  hipLaunchKernelGGL((attn_kernel<4096, 1024, false>), dim3(256), dim3(512), 0,
                     stream, qt, Kt, Vc, (void*)O1, (const float*)nullptr,
                     (const float*)nullptr);
  // stage 2: full queries Q (N=4096) over pooled anchors (P=1024), values O1;
  // fused epilogue y = gamma*out + x
  hipLaunchKernelGGL((attn_kernel<1024, 4096, true>), dim3(1024), dim3(512), 0,
                     stream, Qt, qt, O1, d_out, x, gamma);
}

// Round 2
// 75.643 us; speedup vs baseline: 1.2245x; 1.2245x over previous
//
#include <hip/hip_runtime.h>
#include <hip/hip_bf16.h>

// Problem: B=8, C=64, H=W=64, N=4096, P=1024.
// ws layout (bf16 elements):
//   Kt (B,N,C) @ 0          : stage-1 keys,  row-major over C
//   Vc (B,C,N) @ 2097152    : stage-1 values (channel-major)
//   Qt (B,N,C) @ 4194304    : stage-2 queries
//   qt (B,P,C) @ 6291456    : pooled q (stage-1 queries / stage-2 keys)
//   O1 (B,C,P) @ 6815744    : stage-1 out (stage-2 values)

typedef float  f32x4  __attribute__((ext_vector_type(4)));
typedef __bf16 bf16x8 __attribute__((ext_vector_type(8)));
typedef __bf16 bf16x4 __attribute__((ext_vector_type(4)));

// chunk (16B) XOR swizzle within each 64-chunk (8-row) group
__device__ __forceinline__ int swz(int ch) { return ch ^ ((ch >> 3) & 7); }

// ---------------------------------------------------------------------------
// Kernel 1: four 1x1 convs (+bias), fp32 compute, bf16 outputs in MFMA layouts.
// Grid 1024 = m*256 + b*32 + rp : each block does ONE conv m for one 64c x 128n
// tile (4x the blocks of round-1 -> 3 blocks/CU resident, latency hidden).
// q-branch (m==3): fused 2x2 avg pool via shfl_xor(8).
// ---------------------------------------------------------------------------
__global__ __launch_bounds__(256) void conv4_kernel(
    const float* __restrict__ x,
    const float* __restrict__ wq, const float* __restrict__ bq,
    const float* __restrict__ wQ, const float* __restrict__ bQ,
    const float* __restrict__ wK, const float* __restrict__ bK,
    const float* __restrict__ wV, const float* __restrict__ bV,
    __bf16* __restrict__ Kt, __bf16* __restrict__ Vc,
    __bf16* __restrict__ Qt, __bf16* __restrict__ qt)
{
  __shared__ float xs[64 * 132];   // [c][n0..128] padded
  __shared__ float wsh[64 * 68];   // [c][o] transposed weights, padded

  const int tid = threadIdx.x;
  const int m   = blockIdx.x >> 8;          // conv index, slowest (XCD reuse of x)
  const int b   = (blockIdx.x >> 5) & 7;
  const int rp  = blockIdx.x & 31;
  const int n0  = rp << 7;

  const float* wg = (m == 0) ? wK : (m == 1) ? wV : (m == 2) ? wQ : wq;
  const float* bg = (m == 0) ? bK : (m == 1) ? bV : (m == 2) ? bQ : bq;

  for (int i = tid; i < 64 * 32; i += 256) {
    int c = i >> 5, j = i & 31;
    *(f32x4*)&xs[c * 132 + j * 4] =
        *(const f32x4*)&x[((size_t)(b * 64 + c)) * 4096 + n0 + j * 4];
  }
  for (int i = tid; i < 1024; i += 256) {
    int o = i >> 4, c0 = (i & 15) << 2;
    f32x4 v = *(const f32x4*)&wg[o * 64 + c0];
    wsh[(c0 + 0) * 68 + o] = v[0];
    wsh[(c0 + 1) * 68 + o] = v[1];
    wsh[(c0 + 2) * 68 + o] = v[2];
    wsh[(c0 + 3) * 68 + o] = v[3];
  }
  __syncthreads();

  const int ty = tid >> 4, tx = tid & 15;

  float acc[4][8];
  {
    f32x4 bv = *(const f32x4*)&bg[ty * 4];
#pragma unroll
    for (int i = 0; i < 4; ++i)
#pragma unroll
      for (int j = 0; j < 8; ++j) acc[i][j] = bv[i];
  }

#pragma unroll 4
  for (int c = 0; c < 64; ++c) {
    f32x4 wv = *(const f32x4*)&wsh[c * 68 + ty * 4];
    f32x4 xa = *(const f32x4*)&xs[c * 132 + tx * 8];
    f32x4 xb = *(const f32x4*)&xs[c * 132 + tx * 8 + 4];
#pragma unroll
    for (int i = 0; i < 4; ++i) {
#pragma unroll
      for (int j = 0; j < 4; ++j) {
        acc[i][j]     += wv[i] * xa[j];
        acc[i][j + 4] += wv[i] * xb[j];
      }
    }
  }

  if (m == 0 || m == 2) {            // Kt / Qt : (B,N,C)
    __bf16* dst = (m == 0) ? Kt : Qt;
#pragma unroll
    for (int j = 0; j < 8; ++j) {
      int n = n0 + tx * 8 + j;
      bf16x4 pk;
#pragma unroll
      for (int i = 0; i < 4; ++i) pk[i] = (__bf16)acc[i][j];
      *(bf16x4*)&dst[((size_t)(b * 4096 + n)) * 64 + ty * 4] = pk;
    }
  } else if (m == 1) {               // Vc : (B,C,N)
#pragma unroll
    for (int i = 0; i < 4; ++i) {
      int o = ty * 4 + i;
      bf16x8 pk;
#pragma unroll
      for (int j = 0; j < 8; ++j) pk[j] = (__bf16)acc[i][j];
      *(bf16x8*)&Vc[((size_t)(b * 64 + o)) * 4096 + n0 + tx * 8] = pk;
    }
  } else {                           // q branch: 2x2 avg pool -> qt (B,P,C)
    float pl[4][4];
#pragma unroll
    for (int i = 0; i < 4; ++i)
#pragma unroll
      for (int jj = 0; jj < 4; ++jj)
        pl[i][jj] = acc[i][2 * jj] + acc[i][2 * jj + 1];
#pragma unroll
    for (int i = 0; i < 4; ++i)
#pragma unroll
      for (int jj = 0; jj < 4; ++jj)
        pl[i][jj] += __shfl_xor(pl[i][jj], 8);
    if (tx < 8) {
#pragma unroll
      for (int jj = 0; jj < 4; ++jj) {
        int p = rp * 32 + tx * 4 + jj;
        bf16x4 pk;
#pragma unroll
        for (int i = 0; i < 4; ++i) pk[i] = (__bf16)(0.25f * pl[i][jj]);
        *(bf16x4*)&qt[((size_t)(b * 1024 + p)) * 64 + ty * 4] = pk;
      }
    }
  }
}

// ---------------------------------------------------------------------------
// Stage 1: pooled queries (P=1024) over keys (N=4096). 8 waves =
// {2 q-tiles of 16} x {4 kv-splits of 1024}, 16 rounds of 64 kv.
// Double-buffered LDS, register prefetch 2 rounds ahead, ONE barrier/round.
// LDS: K 2x32KB @0 | V 2x32KB @65536 | P 8x2KB @131072  (144KB)
// ---------------------------------------------------------------------------
__global__ __launch_bounds__(512, 2) void attn1_kernel(
    const __bf16* __restrict__ Qg,   // qt (B,1024,64)
    const __bf16* __restrict__ Kg,   // Kt (B,4096,64)
    const __bf16* __restrict__ Vg,   // Vc (B,64,4096)
    __bf16* __restrict__ outp)       // O1 (B,64,1024)
{
  __shared__ __align__(16) char smem[147456];

  const int tid  = threadIdx.x;
  const int wave = tid >> 6, lane = tid & 63;
  const int lg = (lane >> 4) & 3, lp = lane & 15;
  const int qt = wave & 1, ks = wave >> 1;
  const int b  = blockIdx.x >> 5;
  const int q0 = (blockIdx.x & 31) * 32;

  const __bf16* qg = Qg + ((size_t)(b * 1024 + q0 + qt * 16 + lp)) * 64;
  const bf16x8 qf0 = *(const bf16x8*)(qg + lg * 8);
  const bf16x8 qf1 = *(const bf16x8*)(qg + 32 + lg * 8);

  f32x4 acc[4];
#pragma unroll
  for (int ct = 0; ct < 4; ++ct) acc[ct] = (f32x4){0.f, 0.f, 0.f, 0.f};
  float m_run = -3.0e38f, l_run = 0.0f;

  bf16x8 kreg[4], vreg[4];
  const int sw = swz(tid & 511);
  // per round: thread stages, for each split j, K chunk tid and V chunk tid
  auto load_tile = [&](int r) {
    const __bf16* kb = Kg + (size_t)b * 262144 + (size_t)r * 4096 + tid * 8;
    const __bf16* vb = Vg + ((size_t)(b * 64 + (tid >> 3))) * 4096 + r * 64 + (tid & 7) * 8;
#pragma unroll
    for (int j = 0; j < 4; ++j) {
      kreg[j] = *(const bf16x8*)(kb + (size_t)j * 65536);
      vreg[j] = *(const bf16x8*)(vb + j * 1024);
    }
  };
  auto write_tile = [&](int nb) {
    __bf16* kd = (__bf16*)(smem + nb * 32768);
    __bf16* vd = (__bf16*)(smem + 65536 + nb * 32768);
#pragma unroll
    for (int j = 0; j < 4; ++j) {
      *(bf16x8*)(kd + (j * 512 + sw) * 8) = kreg[j];
      *(bf16x8*)(vd + (j * 512 + sw) * 8) = vreg[j];
    }
  };

  load_tile(0); write_tile(0);
  load_tile(1);
  __syncthreads();

  for (int r = 0; r < 16; ++r) {
    const int cur = r & 1;
    if (r + 1 < 16) write_tile(cur ^ 1);   // tile r+1 into idle buffer
    if (r + 2 < 16) load_tile(r + 2);      // issue loads, hide under compute

    const __bf16* lK = (const __bf16*)(smem + cur * 32768) + ks * 4096;
    const __bf16* lV = (const __bf16*)(smem + 65536 + cur * 32768) + ks * 4096;
    __bf16* lP = (__bf16*)(smem + 131072) + wave * 1024;

    // S^T tile: 64 kv x 16 q
    f32x4 S[4];
#pragma unroll
    for (int mt = 0; mt < 4; ++mt) {
      int ch0 = (mt * 16 + lp) * 8 + lg;
      bf16x8 a0 = *(const bf16x8*)(lK + swz(ch0) * 8);
      bf16x8 a1 = *(const bf16x8*)(lK + swz(ch0 + 4) * 8);
      f32x4 z = (f32x4){0.f, 0.f, 0.f, 0.f};
      z = __builtin_amdgcn_mfma_f32_16x16x32_bf16(a0, qf0, z, 0, 0, 0);
      z = __builtin_amdgcn_mfma_f32_16x16x32_bf16(a1, qf1, z, 0, 0, 0);
      S[mt] = z;
    }

    // online softmax; this lane's query column is p = lp
    float tmax = -3.0e38f;
#pragma unroll
    for (int mt = 0; mt < 4; ++mt)
#pragma unroll
      for (int rr = 0; rr < 4; ++rr) tmax = fmaxf(tmax, S[mt][rr]);
    tmax = fmaxf(tmax, __shfl_xor(tmax, 16));
    tmax = fmaxf(tmax, __shfl_xor(tmax, 32));
    float mnew = fmaxf(m_run, tmax);
    float sc = __expf(m_run - mnew);
    float rs = 0.f;
#pragma unroll
    for (int mt = 0; mt < 4; ++mt)
#pragma unroll
      for (int rr = 0; rr < 4; ++rr) {
        float e = __expf(S[mt][rr] - mnew);
        S[mt][rr] = e;
        rs += e;
      }
    rs += __shfl_xor(rs, 16);
    rs += __shfl_xor(rs, 32);
    l_run = l_run * sc + rs;
    m_run = mnew;
#pragma unroll
    for (int ct = 0; ct < 4; ++ct) acc[ct] *= sc;

    // P -> private LDS [p=16][kv=64] bf16, swizzled
#pragma unroll
    for (int mt = 0; mt < 4; ++mt) {
      bf16x4 pk;
#pragma unroll
      for (int rr = 0; rr < 4; ++rr) pk[rr] = (__bf16)S[mt][rr];
      int boff = lp * 128 + mt * 32 + lg * 8;
      *(bf16x4*)((char*)lP + (boff ^ ((lp & 7) << 4))) = pk;
    }

    // PV: acc(c-tile, p) += V_rows x P_cols
    {
      int chp = lp * 8 + lg;
      bf16x8 pf0 = *(const bf16x8*)(lP + swz(chp) * 8);
      bf16x8 pf1 = *(const bf16x8*)(lP + swz(chp + 4) * 8);
#pragma unroll
      for (int ct = 0; ct < 4; ++ct) {
        int chv = (ct * 16 + lp) * 8 + lg;
        bf16x8 v0 = *(const bf16x8*)(lV + swz(chv) * 8);
        bf16x8 v1 = *(const bf16x8*)(lV + swz(chv + 4) * 8);
        acc[ct] = __builtin_amdgcn_mfma_f32_16x16x32_bf16(v0, pf0, acc[ct], 0, 0, 0);
        acc[ct] = __builtin_amdgcn_mfma_f32_16x16x32_bf16(v1, pf1, acc[ct], 0, 0, 0);
      }
    }
    __syncthreads();
  }

  // ---- cross-kv-split combine ----
  float2* mlb = (float2*)(smem + 131072);
  if (lg == 0) mlb[wave * 16 + lp] = make_float2(m_run, l_run);
  float* cb = (float*)smem;  // [qt][ks][p=16][c=64] fp32 = 32KB
  {
    float* myc = cb + ((size_t)(qt * 4 + ks) * 16 + lp) * 64;
#pragma unroll
    for (int ct = 0; ct < 4; ++ct)
      *(f32x4*)(myc + ct * 16 + lg * 4) = acc[ct];
  }
  __syncthreads();

  if (wave < 2) {
    const int qtt = wave;
    const int nq = q0 + qtt * 16 + lp;
    float mm[4], lv[4];
    float mstar = -3.0e38f;
#pragma unroll
    for (int s = 0; s < 4; ++s) {
      float2 v = mlb[(s * 2 + qtt) * 16 + lp];
      mm[s] = v.x; lv[s] = v.y;
      mstar = fmaxf(mstar, mm[s]);
    }
    float f[4], lstar = 0.f;
#pragma unroll
    for (int s = 0; s < 4; ++s) {
      f[s] = __expf(mm[s] - mstar);
      lstar += lv[s] * f[s];
    }
    float inv = 1.0f / lstar;
#pragma unroll
    for (int ct = 0; ct < 4; ++ct) {
      f32x4 o = (f32x4){0.f, 0.f, 0.f, 0.f};
#pragma unroll
      for (int s = 0; s < 4; ++s) {
        f32x4 t = *(const f32x4*)(cb + ((size_t)(qtt * 4 + s) * 16 + lp) * 64 +
                                  ct * 16 + lg * 4);
        o += f[s] * t;
      }
#pragma unroll
      for (int rr = 0; rr < 4; ++rr) {
        int c = ct * 16 + lg * 4 + rr;
        outp[((size_t)(b * 64 + c)) * 1024 + nq] = (__bf16)(o[rr] * inv);
      }
    }
  }
}

// ---------------------------------------------------------------------------
// Stage 2: full queries (N=4096) over pooled anchors (P=1024). NO kv-split:
// 8 waves x 16 q = 128 q/block all share ONE staged 64-anchor K/V tile per
// round (staging cost /4 vs round-1), 16 rounds, no combine, fused epilogue.
// LDS: K 2x8KB @0 | V 2x8KB @16384 | P 8x2KB @32768  (48KB)
// ---------------------------------------------------------------------------
__global__ __launch_bounds__(512, 2) void attn2_kernel(
    const __bf16* __restrict__ Qg,   // Qt (B,4096,64)
    const __bf16* __restrict__ Kg,   // qt (B,1024,64)
    const __bf16* __restrict__ Vg,   // O1 (B,64,1024)
    float* __restrict__ outp,        // (B,64,4096) f32
    const float* __restrict__ xres,
    const float* __restrict__ gammap)
{
  __shared__ __align__(16) char smem[49152];

  const int tid  = threadIdx.x;
  const int wave = tid >> 6, lane = tid & 63;
  const int lg = (lane >> 4) & 3, lp = lane & 15;
  const int b  = blockIdx.x >> 5;
  const int q0 = (blockIdx.x & 31) * 128;
  const int myq = q0 + wave * 16 + lp;

  const __bf16* qg = Qg + ((size_t)(b * 4096 + myq)) * 64;
  const bf16x8 qf0 = *(const bf16x8*)(qg + lg * 8);
  const bf16x8 qf1 = *(const bf16x8*)(qg + 32 + lg * 8);

  f32x4 acc[4];
#pragma unroll
  for (int ct = 0; ct < 4; ++ct) acc[ct] = (f32x4){0.f, 0.f, 0.f, 0.f};
  float m_run = -3.0e38f, l_run = 0.0f;

  bf16x8 kreg, vreg;
  const int sw = swz(tid & 511);
  auto load_tile = [&](int r) {
    kreg = *(const bf16x8*)(Kg + (size_t)b * 65536 + (size_t)r * 4096 + tid * 8);
    vreg = *(const bf16x8*)(Vg + ((size_t)(b * 64 + (tid >> 3))) * 1024 + r * 64 + (tid & 7) * 8);
  };
  auto write_tile = [&](int nb) {
    *(bf16x8*)((__bf16*)(smem + nb * 8192) + sw * 8) = kreg;
    *(bf16x8*)((__bf16*)(smem + 16384 + nb * 8192) + sw * 8) = vreg;
  };

  load_tile(0); write_tile(0);
  load_tile(1);
  __syncthreads();

  for (int r = 0; r < 16; ++r) {
    const int cur = r & 1;
    if (r + 1 < 16) write_tile(cur ^ 1);
    if (r + 2 < 16) load_tile(r + 2);

    const __bf16* lK = (const __bf16*)(smem + cur * 8192);
    const __bf16* lV = (const __bf16*)(smem + 16384 + cur * 8192);
    __bf16* lP = (__bf16*)(smem + 32768) + wave * 1024;

    f32x4 S[4];
#pragma unroll
    for (int mt = 0; mt < 4; ++mt) {
      int ch0 = (mt * 16 + lp) * 8 + lg;
      bf16x8 a0 = *(const bf16x8*)(lK + swz(ch0) * 8);
      bf16x8 a1 = *(const bf16x8*)(lK + swz(ch0 + 4) * 8);
      f32x4 z = (f32x4){0.f, 0.f, 0.f, 0.f};
      z = __builtin_amdgcn_mfma_f32_16x16x32_bf16(a0, qf0, z, 0, 0, 0);
      z = __builtin_amdgcn_mfma_f32_16x16x32_bf16(a1, qf1, z, 0, 0, 0);
      S[mt] = z;
    }

    float tmax = -3.0e38f;
#pragma unroll
    for (int mt = 0; mt < 4; ++mt)
#pragma unroll
      for (int rr = 0; rr < 4; ++rr) tmax = fmaxf(tmax, S[mt][rr]);
    tmax = fmaxf(tmax, __shfl_xor(tmax, 16));
    tmax = fmaxf(tmax, __shfl_xor(tmax, 32));
    float mnew = fmaxf(m_run, tmax);
    float sc = __expf(m_run - mnew);
    float rs = 0.f;
#pragma unroll
    for (int mt = 0; mt < 4; ++mt)
#pragma unroll
      for (int rr = 0; rr < 4; ++rr) {
        float e = __expf(S[mt][rr] - mnew);
        S[mt][rr] = e;
        rs += e;
      }
    rs += __shfl_xor(rs, 16);
    rs += __shfl_xor(rs, 32);
    l_run = l_run * sc + rs;
    m_run = mnew;
#pragma unroll
    for (int ct = 0; ct < 4; ++ct) acc[ct] *= sc;

#pragma unroll
    for (int mt = 0; mt < 4; ++mt) {
      bf16x4 pk;
#pragma unroll
      for (int rr = 0; rr < 4; ++rr) pk[rr] = (__bf16)S[mt][rr];
      int boff = lp * 128 + mt * 32 + lg * 8;
      *(bf16x4*)((char*)lP + (boff ^ ((lp & 7) << 4))) = pk;
    }

    {
      int chp = lp * 8 + lg;
      bf16x8 pf0 = *(const bf16x8*)(lP + swz(chp) * 8);
      bf16x8 pf1 = *(const bf16x8*)(lP + swz(chp + 4) * 8);
#pragma unroll
      for (int ct = 0; ct < 4; ++ct) {
        int chv = (ct * 16 + lp) * 8 + lg;
        bf16x8 v0 = *(const bf16x8*)(lV + swz(chv) * 8);
        bf16x8 v1 = *(const bf16x8*)(lV + swz(chv + 4) * 8);
        acc[ct] = __builtin_amdgcn_mfma_f32_16x16x32_bf16(v0, pf0, acc[ct], 0, 0, 0);
        acc[ct] = __builtin_amdgcn_mfma_f32_16x16x32_bf16(v1, pf1, acc[ct], 0, 0, 0);
      }
    }
    __syncthreads();
  }

  // fused epilogue: y = gamma * (acc/l) + x
  const float inv = 1.0f / l_run;
  const float g0 = gammap[0];
#pragma unroll
  for (int ct = 0; ct < 4; ++ct)
#pragma unroll
    for (int rr = 0; rr < 4; ++rr) {
      int c = ct * 16 + lg * 4 + rr;
      size_t oi = ((size_t)(b * 64 + c)) * 4096 + myq;
      outp[oi] = g0 * (acc[ct][rr] * inv) + xres[oi];
    }
}

// ---------------------------------------------------------------------------
extern "C" void kernel_launch(void* const* d_in, const int* in_sizes, int n_in,
                              void* d_out, int out_size, void* d_ws, size_t ws_size,
                              hipStream_t stream) {
  const float* x     = (const float*)d_in[0];
  const float* wq    = (const float*)d_in[1];
  const float* bq    = (const float*)d_in[2];
  const float* wQ    = (const float*)d_in[3];
  const float* bQ    = (const float*)d_in[4];
  const float* wK    = (const float*)d_in[5];
  const float* bK    = (const float*)d_in[6];
  const float* wV    = (const float*)d_in[7];
  const float* bV    = (const float*)d_in[8];
  const float* gamma = (const float*)d_in[9];

  __bf16* ws = (__bf16*)d_ws;
  __bf16* Kt = ws;
  __bf16* Vc = ws + 2097152;
  __bf16* Qt = ws + 4194304;
  __bf16* qt = ws + 6291456;
  __bf16* O1 = ws + 6815744;

  hipLaunchKernelGGL(conv4_kernel, dim3(1024), dim3(256), 0, stream,
                     x, wq, bq, wQ, bQ, wK, bK, wV, bV, Kt, Vc, Qt, qt);
  hipLaunchKernelGGL(attn1_kernel, dim3(256), dim3(512), 0, stream,
                     qt, Kt, Vc, O1);
  hipLaunchKernelGGL(attn2_kernel, dim3(256), dim3(512), 0, stream,
                     Qt, qt, O1, (float*)d_out, x, gamma);
}